// Round 3
// baseline (1142.757 us; speedup 1.0000x reference)
//
#include <hip/hip_runtime.h>
#include <stdint.h>

// TinyGRU R12: 16 waves/block (1024 thr), 1 row-tile per wave.
// R11 post-mortem: blocks spread 1/CU -> only 2 waves/SIMD; per-SIMD pipe
// load 57 MFMA (~1106cyc) vs 2141cyc step => pipe 52% busy, ~1000cyc of
// exposed serial latency (gate chain + LDS round-trip + barrier) that 2
// waves can't hide. Fix: same per-SIMD pipe load through 4 waves/SIMD:
// each layer split 8 waves x 1 tile (wave w owns rows [16w,16w+16) of all
// 3 gates -> lane computes full gate set for one h value). Per-wave issue
// halves, per-wave gate VALU halves, overlap doubles.
// Register discipline (16 waves/CU => <=128 regs/wave): L0 ~117, L1 ~120;
// L1's 4-step batch accs Y stashed to LDS (24KB, lane-contig f32, conflict
// free) once per group, 3x ds_read_b32 per step. Ring slot stride padded
// 576->584 halves (1168B) to kill R11's 3.1M bank conflicts (slot stride
// was bank-aligned). All math identical to R11 (f32 accs, f16 operands).

typedef _Float16 half_t;
typedef _Float16 half8 __attribute__((ext_vector_type(8)));
typedef __fp16  fp16x2 __attribute__((ext_vector_type(2)));
typedef float f32x4 __attribute__((ext_vector_type(4)));

#define SS 1024
#define CPB 4
#define NBLK 128
#define CT 4              // x chunk depth (steps per group)
#define HC 144            // h row stride (f16): 288B, 16B-aligned
#define XC 72             // x chain stride (f16): 144B, 16B-aligned
#define SLOTH 584         // padded h0 ring slot stride (1168B, 16B-aligned)
#define XSLAB 296         // padded x step-slab stride (592B, 16B-aligned)

#define MFMA16(a, b, c) __builtin_amdgcn_mfma_f32_16x16x32_f16(a, b, c, 0, 0, 0)

// lgkmcnt(0), vmcnt=63 (no wait), expcnt=7 (no wait)  [gfx9 encoding]
#define BAR() do { __builtin_amdgcn_sched_barrier(0);                 \
                   __builtin_amdgcn_s_waitcnt(0xC07F);                \
                   __builtin_amdgcn_s_barrier();                      \
                   __builtin_amdgcn_sched_barrier(0); } while (0)

__device__ __forceinline__ float sigmoidf_(float x) {
    return __builtin_amdgcn_rcpf(1.0f + __expf(-x));
}
__device__ __forceinline__ float tanhf_(float x) {
    return 1.0f - 2.0f * __builtin_amdgcn_rcpf(1.0f + __expf(2.0f * x));
}
union H8 { half8 v; fp16x2 p[4]; };
__device__ __forceinline__ half8 pack8(f32x4 a, f32x4 b) {
    H8 u;
    u.p[0] = __builtin_amdgcn_cvt_pkrtz(a[0], a[1]);
    u.p[1] = __builtin_amdgcn_cvt_pkrtz(a[2], a[3]);
    u.p[2] = __builtin_amdgcn_cvt_pkrtz(b[0], b[1]);
    u.p[3] = __builtin_amdgcn_cvt_pkrtz(b[2], b[3]);
    return u.v;
}
__device__ __forceinline__ half8 cvt8(const float* p) {
    return pack8(*(const f32x4*)p, *(const f32x4*)(p + 4));
}

__global__ __launch_bounds__(1024, 4)
void gru_fused(const float* __restrict__ x,
               const float* __restrict__ Wih0, const float* __restrict__ Whh0,
               const float* __restrict__ bih0, const float* __restrict__ bhh0,
               const float* __restrict__ Wih1, const float* __restrict__ Whh1,
               const float* __restrict__ bih1, const float* __restrict__ bhh1,
               const float* __restrict__ fcw, const float* __restrict__ fcb,
               float* __restrict__ out)
{
    const int tid  = threadIdx.x;
    const int w    = tid >> 6;
    const int lane = tid & 63;
    const int quad = lane >> 4;
    const int col  = lane & 15;
    const int c3   = col & 3;      // batch: step-in-group
    const int ch4  = col >> 2;     // chain
    const int cb   = blockIdx.x * CPB;

    __shared__ alignas(16) half_t s_x[2][CT][XSLAB];
    __shared__ alignas(16) half_t s_h0[8][SLOTH];     // 8-deep ring, padded
    __shared__ alignas(16) half_t s_h1[2][CPB * HC];
    __shared__ float s_Yr[4][512], s_Yz[4][512], s_Yn[4][512]; // L1 batch stash

    // zero: h0[-1] in ring slot 7; h1[-1] in parity slot 1
    for (int i = tid; i < CPB * HC; i += 1024) {
        s_h0[7][i] = (half_t)0.0f;
        s_h1[1][i] = (half_t)0.0f;
    }

    // ---- x staging: tid<256 (waves 0-3, all layer-0). 2 chunks ahead ----
    const int c  = (tid >> 6) & 3;
    const int sc = tid & 63;
    const float* xrow = x + (size_t)(cb + c) * SS * 64 + sc;
    float gq[CT];
    if (tid < 256) {
        float t[CT];
#pragma unroll
        for (int i = 0; i < CT; ++i) t[i] = xrow[i * 64];
#pragma unroll
        for (int i = 0; i < CT; ++i) s_x[0][i][c * XC + sc] = (half_t)t[i];
#pragma unroll
        for (int i = 0; i < CT; ++i) t[i] = xrow[(CT + i) * 64];
#pragma unroll
        for (int i = 0; i < CT; ++i) s_x[1][i][c * XC + sc] = (half_t)t[i];
#pragma unroll
        for (int i = 0; i < CT; ++i) gq[i] = xrow[(2 * CT + i) * 64];
    }
    __syncthreads();

    const int aoff = ch4 * HC + quad * 8;   // h-read base (halves)

    if (w < 8) {
        // ===== layer-0 waves: 1 row-tile (rows [16w,16w+16) of each gate) =====
        const int rr = w * 16 + col;
        half8 Bx[3][2], Bh[3][4];
#pragma unroll
        for (int gg = 0; gg < 3; ++gg) {
#pragma unroll
            for (int s = 0; s < 2; ++s)
                Bx[gg][s] = cvt8(Wih0 + (rr + gg * 128) * 64 + s * 32 + quad * 8);
#pragma unroll
            for (int s = 0; s < 4; ++s)
                Bh[gg][s] = cvt8(Whh0 + (rr + gg * 128) * 128 + s * 32 + quad * 8);
        }
        const float bR  = bih0[rr] + bhh0[rr];
        const float bZ  = bih0[128 + rr] + bhh0[128 + rr];
        const float bNI = bih0[256 + rr];
        const float bNH = bhh0[256 + rr];
        float hp = 0.0f;
        f32x4 XAr, XAz, XAn;   // batched xg0 for current group (+bias)

#define L0_BATCH(BUF)                                                        \
        {                                                                    \
            const half_t* xp = &s_x[(BUF)][c3][ch4 * XC + quad * 8];         \
            half8 a0 = *(const half8*)xp;                                    \
            half8 a1 = *(const half8*)(xp + 32);                             \
            XAr = (f32x4){bR,  bR,  bR,  bR};                                \
            XAz = (f32x4){bZ,  bZ,  bZ,  bZ};                                \
            XAn = (f32x4){bNI, bNI, bNI, bNI};                               \
            XAr = MFMA16(a0, Bx[0][0], XAr);  XAr = MFMA16(a1, Bx[0][1], XAr);\
            XAz = MFMA16(a0, Bx[1][0], XAz);  XAz = MFMA16(a1, Bx[1][1], XAz);\
            XAn = MFMA16(a0, Bx[2][0], XAn);  XAn = MFMA16(a1, Bx[2][1], XAn);\
        }

        L0_BATCH(0);   // xg0 for group 0 (chunk 0, pre-synced)

        for (int g = 0; g < 256; ++g) {
#pragma unroll
            for (int j = 0; j < 4; ++j) {
                const int u = 4 * g + j;
                f32x4 ar  = {0.f, 0.f, 0.f, 0.f};
                f32x4 az  = {0.f, 0.f, 0.f, 0.f};
                f32x4 anh = {bNH, bNH, bNH, bNH};
                const half_t* hb = &s_h0[(u - 1) & 7][aoff];
#pragma unroll
                for (int s = 0; s < 4; ++s) {
                    half8 ah = *(const half8*)(hb + s * 32);
                    ar  = MFMA16(ah, Bh[0][s], ar);
                    az  = MFMA16(ah, Bh[1][s], az);
                    anh = MFMA16(ah, Bh[2][s], anh);
                }
                float r = sigmoidf_(ar[0] + XAr[j]);
                float z = sigmoidf_(az[0] + XAz[j]);
                float n = tanhf_(XAn[j] + r * anh[0]);
                hp = n + z * (hp - n);
                s_h0[u & 7][quad * HC + rr] = (half_t)hp;
                if (j == 3) {
                    if (tid < 256) {
                        if (g + 2 < 256) {        // publish chunk g+2 -> buf g&1
#pragma unroll
                            for (int i = 0; i < CT; ++i)
                                s_x[g & 1][i][c * XC + sc] = (half_t)gq[i];
                        }
                        if (g + 3 < 256) {        // issue load chunk g+3
#pragma unroll
                            for (int i = 0; i < CT; ++i)
                                gq[i] = xrow[(size_t)((g + 3) * CT + i) * 64];
                        }
                    }
                    if (g < 255) L0_BATCH((g + 1) & 1);   // xg0 for group g+1
                }
                BAR();
            }
        }
        BAR(); BAR(); BAR(); BAR();   // intervals 1024..1027 (L1 tail)
#undef L0_BATCH
    } else {
        // ===== layer-1 waves (lag 4): 1 row-tile each =====
        const int w1 = w - 8;
        const int rr = w1 * 16 + col;
        half8 Bx1[3][4], Bh1[3][4];
#pragma unroll
        for (int gg = 0; gg < 3; ++gg) {
#pragma unroll
            for (int s = 0; s < 4; ++s) {
                Bx1[gg][s] = cvt8(Wih1 + (rr + gg * 128) * 128 + s * 32 + quad * 8);
                Bh1[gg][s] = cvt8(Whh1 + (rr + gg * 128) * 128 + s * 32 + quad * 8);
            }
        }
        const float bR  = bih1[rr] + bhh1[rr];
        const float bZ  = bih1[128 + rr] + bhh1[128 + rr];
        const float bNI = bih1[256 + rr];
        const float bNH = bhh1[256 + rr];
        float hp = 0.0f;
        const int yb = w1 * 64 + lane;

        BAR(); BAR(); BAR(); BAR();  // intervals 0..3 (L0 warms up)
        for (int g = 1; g <= 256; ++g) {
#pragma unroll
            for (int j = 0; j < 4; ++j) {
                if (j == 0) {
                    // batch xg1 for L1-group g-1: h0 ring slots (G&1)*4 + c3
                    const int slot = ((g - 1) & 1) * 4 + c3;
                    const half_t* bp = &s_h0[slot][aoff];
                    f32x4 Yr = (f32x4){bR,  bR,  bR,  bR};
                    f32x4 Yz = (f32x4){bZ,  bZ,  bZ,  bZ};
                    f32x4 Yn = (f32x4){bNI, bNI, bNI, bNI};
#pragma unroll
                    for (int s = 0; s < 4; ++s) {
                        half8 ax = *(const half8*)(bp + s * 32);
                        Yr = MFMA16(ax, Bx1[0][s], Yr);
                        Yz = MFMA16(ax, Bx1[1][s], Yz);
                        Yn = MFMA16(ax, Bx1[2][s], Yn);
                    }
#pragma unroll
                    for (int j2 = 0; j2 < 4; ++j2) {   // stash (frees 12 regs)
                        s_Yr[j2][yb] = Yr[j2];
                        s_Yz[j2][yb] = Yz[j2];
                        s_Yn[j2][yb] = Yn[j2];
                    }
                }
                // recurrent h1 part for step v = 4(g-1)+j
                f32x4 ar  = {0.f, 0.f, 0.f, 0.f};
                f32x4 az  = {0.f, 0.f, 0.f, 0.f};
                f32x4 anh = {bNH, bNH, bNH, bNH};
                const half_t* hb = &s_h1[(j + 1) & 1][aoff];
#pragma unroll
                for (int s = 0; s < 4; ++s) {
                    half8 ah = *(const half8*)(hb + s * 32);
                    ar  = MFMA16(ah, Bh1[0][s], ar);
                    az  = MFMA16(ah, Bh1[1][s], az);
                    anh = MFMA16(ah, Bh1[2][s], anh);
                }
                float yr = s_Yr[j][yb];
                float yz = s_Yz[j][yb];
                float yn = s_Yn[j][yb];
                float r = sigmoidf_(ar[0] + yr);
                float z = sigmoidf_(az[0] + yz);
                float n = tanhf_(yn + r * anh[0]);
                hp = n + z * (hp - n);
                s_h1[j & 1][quad * HC + rr] = (half_t)hp;
                BAR();
            }
        }
    }

    // ---- FC epilogue: h1[1023] in s_h1[1] ----
    if (tid < 40) {
        const int ch = tid / 10, cl = tid - ch * 10;
        float acc = fcb[cl];
        const float* wrp = fcw + cl * 128;
        const half_t* hv = &s_h1[1][ch * HC];
#pragma unroll 8
        for (int k = 0; k < 128; ++k) acc += (float)hv[k] * wrp[k];
        out[(cb + ch) * 10 + cl] = acc;
    }
}

extern "C" void kernel_launch(void* const* d_in, const int* in_sizes, int n_in,
                              void* d_out, int out_size, void* d_ws, size_t ws_size,
                              hipStream_t stream) {
    const float* x    = (const float*)d_in[0];
    const float* Wih0 = (const float*)d_in[1];
    const float* Whh0 = (const float*)d_in[2];
    const float* bih0 = (const float*)d_in[3];
    const float* bhh0 = (const float*)d_in[4];
    const float* Wih1 = (const float*)d_in[5];
    const float* Whh1 = (const float*)d_in[6];
    const float* bih1 = (const float*)d_in[7];
    const float* bhh1 = (const float*)d_in[8];
    const float* fcw  = (const float*)d_in[9];
    const float* fcb  = (const float*)d_in[10];

    gru_fused<<<NBLK, 1024, 0, stream>>>(x, Wih0, Whh0, bih0, bhh0,
                                         Wih1, Whh1, bih1, bhh1,
                                         fcw, fcb, (float*)d_out);
}

// Round 4
// 1082.648 us; speedup vs baseline: 1.0555x; 1.0555x over previous
//
#include <hip/hip_runtime.h>
#include <stdint.h>

// TinyGRU R13: two-phase interval — each layer's gate hides under the OTHER
// layer's MFMA issue.
// R12 post-mortem: barrier-locked waves convoy; adding waves added contention
// (MfmaUtil 22.5->18.9, step 2141->2486). R11's step = 1106cyc issue + ~1035
// serial (gate chain + post-barrier ds_read + drain), serial because all
// waves align phases. R13: every wave owns row-tile w of BOTH layers.
//  PH1: L1 MFMAs (rec v=u-5 on h1; xg1 batch from old h0 ring slots, weights
//       from LDS) + interleaved L0 gate(u-1) (+h0 write) + x staging. BAR.
//  PH2: L0 MFMAs (rec u on h0 just synced; xg0 batch) + interleaved L1
//       gate(v) (+h1 write). BAR.
// Issue per SIMD unchanged (57/step); every serial chain now has ~470cyc of
// independent MFMA under it. 2 barriers/step (2058 total). Wih1 in LDS
// (12 b128/group, computed one interval before first gate use) keeps VGPR
// <=256 at 2 waves/SIMD. All branches wave-uniform; carries (L0 acc[0]
// scalars) cross the ph2->ph1 barrier in regs. Same math as R11 (f32 accs).

typedef _Float16 half_t;
typedef _Float16 half8 __attribute__((ext_vector_type(8)));
typedef __fp16  fp16x2 __attribute__((ext_vector_type(2)));
typedef float f32x4 __attribute__((ext_vector_type(4)));

#define SS 1024
#define CPB 4
#define NBLK 128
#define CT 4              // x chunk depth (steps per group)
#define HC 144            // h row stride (f16): 288B, 16B-aligned
#define XC 72             // x chain stride (f16): 144B, 16B-aligned
#define SLOTH 584         // h0 ring slot stride (1168B): slot -> +4 banks
#define W1S 136           // s_w1x row stride (272B): row -> +4 banks
#define LAG 5             // L1 lags 5 steps

#define MFMA16(a, b, c) __builtin_amdgcn_mfma_f32_16x16x32_f16(a, b, c, 0, 0, 0)

// lgkmcnt(0), vmcnt=63 (no wait), expcnt=7 (no wait)  [gfx9 encoding]
#define BAR() do { __builtin_amdgcn_sched_barrier(0);                 \
                   __builtin_amdgcn_s_waitcnt(0xC07F);                \
                   __builtin_amdgcn_s_barrier();                      \
                   __builtin_amdgcn_sched_barrier(0); } while (0)

__device__ __forceinline__ float sigmoidf_(float x) {
    return __builtin_amdgcn_rcpf(1.0f + __expf(-x));
}
__device__ __forceinline__ float tanhf_(float x) {
    return 1.0f - 2.0f * __builtin_amdgcn_rcpf(1.0f + __expf(2.0f * x));
}
union H8 { half8 v; fp16x2 p[4]; };
__device__ __forceinline__ half8 pack8(f32x4 a, f32x4 b) {
    H8 u;
    u.p[0] = __builtin_amdgcn_cvt_pkrtz(a[0], a[1]);
    u.p[1] = __builtin_amdgcn_cvt_pkrtz(a[2], a[3]);
    u.p[2] = __builtin_amdgcn_cvt_pkrtz(b[0], b[1]);
    u.p[3] = __builtin_amdgcn_cvt_pkrtz(b[2], b[3]);
    return u.v;
}
__device__ __forceinline__ half8 cvt8(const float* p) {
    return pack8(*(const f32x4*)p, *(const f32x4*)(p + 4));
}

__global__ __launch_bounds__(512, 2)
void gru_fused(const float* __restrict__ x,
               const float* __restrict__ Wih0, const float* __restrict__ Whh0,
               const float* __restrict__ bih0, const float* __restrict__ bhh0,
               const float* __restrict__ Wih1, const float* __restrict__ Whh1,
               const float* __restrict__ bih1, const float* __restrict__ bhh1,
               const float* __restrict__ fcw, const float* __restrict__ fcb,
               float* __restrict__ out)
{
    const int tid  = threadIdx.x;
    const int w    = tid >> 6;
    const int lane = tid & 63;
    const int quad = lane >> 4;
    const int col  = lane & 15;
    const int c3   = col & 3;      // batch: step-in-group
    const int ch4  = col >> 2;     // chain
    const int cb   = blockIdx.x * CPB;

    __shared__ alignas(16) half_t s_x[2][CT][CPB * XC];
    __shared__ alignas(16) half_t s_h0[8][SLOTH];       // 8-deep ring
    __shared__ alignas(16) half_t s_h1[2][CPB * HC];
    __shared__ alignas(16) half_t s_w1x[3 * 128 * W1S]; // Wih1 (f16, padded)

    // zero: h0[-1] in ring slot 7; h1[-1] in parity slot 1
    for (int i = tid; i < CPB * HC; i += 512) {
        s_h0[7][i] = (half_t)0.0f;
        s_h1[1][i] = (half_t)0.0f;
    }
    // Wih1 -> LDS (f32 -> f16), coalesced
    for (int idx = tid; idx < 384 * 128; idx += 512) {
        const int r = idx >> 7, k = idx & 127;
        s_w1x[r * W1S + k] = (half_t)Wih1[idx];
    }

    // ---- per-wave weights (row-tile w of BOTH layers) ----
    const int rr = w * 16 + col;
    half8 B0x[3][2], B0h[3][4], B1h[3][4];
#pragma unroll
    for (int gg = 0; gg < 3; ++gg) {
#pragma unroll
        for (int s = 0; s < 2; ++s)
            B0x[gg][s] = cvt8(Wih0 + (rr + gg * 128) * 64 + s * 32 + quad * 8);
#pragma unroll
        for (int s = 0; s < 4; ++s) {
            B0h[gg][s] = cvt8(Whh0 + (rr + gg * 128) * 128 + s * 32 + quad * 8);
            B1h[gg][s] = cvt8(Whh1 + (rr + gg * 128) * 128 + s * 32 + quad * 8);
        }
    }
    const float b0r  = bih0[rr] + bhh0[rr];
    const float b0z  = bih0[128 + rr] + bhh0[128 + rr];
    const float b0ni = bih0[256 + rr];
    const float b0nh = bhh0[256 + rr];
    const float b1r  = bih1[rr] + bhh1[rr];
    const float b1z  = bih1[128 + rr] + bhh1[128 + rr];
    const float b1ni = bih1[256 + rr];
    const float b1nh = bhh1[256 + rr];

    // ---- x staging prologue: publish chunks 0,1; chunk 2 -> gq ----
    const int c  = (tid >> 6) & 3;
    const int sc = tid & 63;
    const float* xrow = x + (size_t)(cb + c) * SS * 64 + sc;
    float gq[CT];
    if (tid < 256) {
        float t[CT];
#pragma unroll
        for (int i = 0; i < CT; ++i) t[i] = xrow[i * 64];
#pragma unroll
        for (int i = 0; i < CT; ++i) s_x[0][i][c * XC + sc] = (half_t)t[i];
#pragma unroll
        for (int i = 0; i < CT; ++i) t[i] = xrow[(CT + i) * 64];
#pragma unroll
        for (int i = 0; i < CT; ++i) s_x[1][i][c * XC + sc] = (half_t)t[i];
#pragma unroll
        for (int i = 0; i < CT; ++i) gq[i] = xrow[(2 * CT + i) * 64];
    }
    __syncthreads();

    const int aoff = ch4 * HC + quad * 8;   // within-slot h-read base (halves)
    const int wix  = quad * HC + rr;        // h-write index (halves)

    f32x4 XAr, XAz, XAn;        // L0 batched xg0 (+bias), group g=u>>2
    f32x4 Yr, Yz, Yn;           // L1 batched xg1 (+bias), group G=(u-LAG)>>2
    float c0r = 0.f, c0z = 0.f, c0nh = 0.f;   // L0 acc carry (ph2 -> ph1)
    float hp0 = 0.0f, hp1 = 0.0f;

    for (int u = 0; u < SS + LAG; ++u) {
        const int l1on = (u >= LAG);
        // ================= PHASE 1 (L1 MFMAs + L0 gate) =================
        f32x4 ar1, az1, anh1;
        if (l1on && ((u - LAG) & 3) == 0) {
            // xg1 batch for L1 group G: h0 slots (G&1)*4 + c3 (age 1-4)
            const int G = (u - LAG) >> 2;
            const half_t* bp = &s_h0[(G & 1) * 4 + c3][aoff];
            Yr = (f32x4){b1r,  b1r,  b1r,  b1r};
            Yz = (f32x4){b1z,  b1z,  b1z,  b1z};
            Yn = (f32x4){b1ni, b1ni, b1ni, b1ni};
#pragma unroll
            for (int s = 0; s < 4; ++s) {
                half8 ax = *(const half8*)(bp + s * 32);
                const int ko = s * 32 + quad * 8;
                half8 w0 = *(const half8*)&s_w1x[(rr      ) * W1S + ko];
                half8 w1 = *(const half8*)&s_w1x[(rr + 128) * W1S + ko];
                half8 w2 = *(const half8*)&s_w1x[(rr + 256) * W1S + ko];
                Yr = MFMA16(ax, w0, Yr);
                Yz = MFMA16(ax, w1, Yz);
                Yn = MFMA16(ax, w2, Yn);
            }
        }
        if (l1on) {
            // L1 recurrent for step v = u-LAG (reads h1[v-1], slot u&1)
            const half_t* hb = &s_h1[u & 1][aoff];
            ar1  = (f32x4){0.f, 0.f, 0.f, 0.f};
            az1  = (f32x4){0.f, 0.f, 0.f, 0.f};
            anh1 = (f32x4){b1nh, b1nh, b1nh, b1nh};
#pragma unroll
            for (int s = 0; s < 4; ++s) {
                half8 ah = *(const half8*)(hb + s * 32);
                ar1  = MFMA16(ah, B1h[0][s], ar1);
                az1  = MFMA16(ah, B1h[1][s], az1);
                anh1 = MFMA16(ah, B1h[2][s], anh1);
            }
        }
        if (u >= 1 && u <= SS) {
            // L0 gate for step u-1 (carries from ph2 of u-1) -> write h0[u-1]
            const int up = u - 1;
            float r = sigmoidf_(c0r + XAr[up & 3]);
            float z = sigmoidf_(c0z + XAz[up & 3]);
            float n = tanhf_(XAn[up & 3] + r * c0nh);
            hp0 = n + z * (hp0 - n);
            s_h0[up & 7][wix] = (half_t)hp0;
        }
        if ((u & 3) == 3 && u < SS && tid < 256) {
            const int g = u >> 2;
            if (g + 2 < 256) {            // publish chunk g+2 -> buf g&1
#pragma unroll
                for (int i = 0; i < CT; ++i)
                    s_x[g & 1][i][c * XC + sc] = (half_t)gq[i];
            }
            if (g + 3 < 256) {            // issue load chunk g+3
#pragma unroll
                for (int i = 0; i < CT; ++i)
                    gq[i] = xrow[(size_t)((g + 3) * CT + i) * 64];
            }
        }
        BAR();
        // ================= PHASE 2 (L0 MFMAs + L1 gate) =================
        if (u < SS) {
            // L0 recurrent for step u (reads h0[u-1], just synced)
            const half_t* hb = &s_h0[(u - 1) & 7][aoff];
            f32x4 a_r = {0.f, 0.f, 0.f, 0.f};
            f32x4 a_z = {0.f, 0.f, 0.f, 0.f};
            f32x4 a_n = {b0nh, b0nh, b0nh, b0nh};
#pragma unroll
            for (int s = 0; s < 4; ++s) {
                half8 ah = *(const half8*)(hb + s * 32);
                a_r = MFMA16(ah, B0h[0][s], a_r);
                a_z = MFMA16(ah, B0h[1][s], a_z);
                a_n = MFMA16(ah, B0h[2][s], a_n);
            }
            c0r = a_r[0]; c0z = a_z[0]; c0nh = a_n[0];
            if ((u & 3) == 0) {
                // xg0 batch for L0 group g = u>>2 (chunk g in buf g&1)
                const int g = u >> 2;
                const half_t* xp = &s_x[g & 1][c3][ch4 * XC + quad * 8];
                half8 a0 = *(const half8*)xp;
                half8 a1 = *(const half8*)(xp + 32);
                XAr = (f32x4){b0r,  b0r,  b0r,  b0r};
                XAz = (f32x4){b0z,  b0z,  b0z,  b0z};
                XAn = (f32x4){b0ni, b0ni, b0ni, b0ni};
                XAr = MFMA16(a0, B0x[0][0], XAr); XAr = MFMA16(a1, B0x[0][1], XAr);
                XAz = MFMA16(a0, B0x[1][0], XAz); XAz = MFMA16(a1, B0x[1][1], XAz);
                XAn = MFMA16(a0, B0x[2][0], XAn); XAn = MFMA16(a1, B0x[2][1], XAn);
            }
        }
        if (l1on) {
            // L1 gate for step v (accs from ph1 of this interval) -> h1[v]
            const int v = u - LAG;
            float r = sigmoidf_(ar1[0] + Yr[v & 3]);
            float z = sigmoidf_(az1[0] + Yz[v & 3]);
            float n = tanhf_(Yn[v & 3] + r * anh1[0]);
            hp1 = n + z * (hp1 - n);
            s_h1[v & 1][wix] = (half_t)hp1;
        }
        BAR();
    }

    // ---- FC epilogue: h1[1023] in s_h1[1] ----
    if (tid < 40) {
        const int ch = tid / 10, cl = tid - ch * 10;
        float acc = fcb[cl];
        const float* wrp = fcw + cl * 128;
        const half_t* hv = &s_h1[1][ch * HC];
#pragma unroll 8
        for (int k = 0; k < 128; ++k) acc += (float)hv[k] * wrp[k];
        out[(cb + ch) * 10 + cl] = acc;
    }
}

extern "C" void kernel_launch(void* const* d_in, const int* in_sizes, int n_in,
                              void* d_out, int out_size, void* d_ws, size_t ws_size,
                              hipStream_t stream) {
    const float* x    = (const float*)d_in[0];
    const float* Wih0 = (const float*)d_in[1];
    const float* Whh0 = (const float*)d_in[2];
    const float* bih0 = (const float*)d_in[3];
    const float* bhh0 = (const float*)d_in[4];
    const float* Wih1 = (const float*)d_in[5];
    const float* Whh1 = (const float*)d_in[6];
    const float* bih1 = (const float*)d_in[7];
    const float* bhh1 = (const float*)d_in[8];
    const float* fcw  = (const float*)d_in[9];
    const float* fcb  = (const float*)d_in[10];

    gru_fused<<<NBLK, 512, 0, stream>>>(x, Wih0, Whh0, bih0, bhh0,
                                        Wih1, Whh1, bih1, bhh1,
                                        fcw, fcb, (float*)d_out);
}